// Round 1
// baseline (166.461 us; speedup 1.0000x reference)
//
#include <hip/hip_runtime.h>

// Problem constants (from reference)
#define T_TREES 200
#define BATCH   2048
#define D_FEAT  512
#define N_NODE  64
#define LR      0.01f

typedef __attribute__((__ext_vector_type__(8))) __bf16 bf16x8;
typedef __attribute__((__ext_vector_type__(4))) float  f32x4;

__device__ __forceinline__ unsigned short f32_to_bf16(float f) {
    unsigned u = __float_as_uint(f);
    u += 0x7FFFu + ((u >> 16) & 1u);   // RNE
    return (unsigned short)(u >> 16);
}

// async global->LDS, 16B per lane. LDS dest semantics: wave-uniform base + lane*16,
// we pass the per-lane pointer consistent with that (m104/m108).
__device__ __forceinline__ void gload_lds16(const void* g, void* l) {
    __builtin_amdgcn_global_load_lds(
        (__attribute__((address_space(1))) void*)(void*)g,
        (__attribute__((address_space(3))) void*)l,
        16, 0, 0);
}

// ---------------- prep kernels ----------------

// x [2048][512] f32 -> bf16 (same layout)
__global__ void prep_x(const float* __restrict__ x, unsigned short* __restrict__ xb) {
    int i = blockIdx.x * 256 + threadIdx.x;           // 262144 float4 groups
    float4 v = ((const float4*)x)[i];
    ushort4 o;
    o.x = f32_to_bf16(v.x); o.y = f32_to_bf16(v.y);
    o.z = f32_to_bf16(v.z); o.w = f32_to_bf16(v.w);
    ((ushort4*)xb)[i] = o;
}

// w_t [t][d][n] f32 -> w_bt [t][n][d] bf16 (transposed per tree)
__global__ void prep_wt(const float* __restrict__ w_t, unsigned short* __restrict__ w_bt) {
    int i  = blockIdx.x * 256 + threadIdx.x;          // 1,638,400 = 200*64*128 (4 d's each)
    int d4 = i & 127;
    int tn = i >> 7;
    int n  = tn & 63;
    int t  = tn >> 6;
    const float* src = w_t + t * (D_FEAT * N_NODE) + d4 * (4 * N_NODE) + n;
    ushort4 o;
    o.x = f32_to_bf16(src[0]);
    o.y = f32_to_bf16(src[64]);
    o.z = f32_to_bf16(src[128]);
    o.w = f32_to_bf16(src[192]);
    ((ushort4*)w_bt)[i] = o;
}

// w_d [t][n][15] f32 -> w_dt [t][16][64] bf16 (transposed, col 15 zero-padded)
__global__ void prep_wd(const float* __restrict__ w_d, unsigned short* __restrict__ w_dt) {
    int i = blockIdx.x * 256 + threadIdx.x;           // 204800 = 200*16*64
    int n = i & 63;
    int l = (i >> 6) & 15;
    int t = i >> 10;
    float v = (l < 15) ? w_d[(t * 64 + n) * 15 + l] : 0.f;
    w_dt[i] = f32_to_bf16(v);
}

// ---------------- main fused kernel ----------------
// One block = one tree x 128 batch rows. 256 threads (4 waves).
// Wave w owns rows [w*32, w*32+32). GEMM1: [128,512]@[512,64] via mfma 16x16x32 bf16.
// LDS XOR swizzle: cell(row, kg) stored at column-group kg, holding data of
// k-group (kg ^ (row&7)) -> dense for global_load_lds, <=2-way conflicts on ds_read_b128.
__global__ __launch_bounds__(256) void gbdt_main(
    const unsigned short* __restrict__ x_bf,   // [2048][512] bf16
    const unsigned short* __restrict__ w_bt,   // [200][64][512] bf16
    const unsigned short* __restrict__ w_dt,   // [200][16][64] bf16
    const float* __restrict__ b_t,             // [200][64]
    const float* __restrict__ b_d,             // [200][15]
    const float* __restrict__ w_l,             // [200][16]
    const float* __restrict__ b_l,             // [200]
    float* __restrict__ f_ws)                  // [200][2048]
{
    __shared__ alignas(16) char smem[27136];
    unsigned short* Alds = (unsigned short*)smem;            // 16 KB: A tile 128x64 / later h
    unsigned short* Blds = (unsigned short*)(smem + 16384);  // 8 KB: B tile 64x64 / later w_dt 16x64
    float*          Plds = (float*)(smem + 18432);           // 8.5 KB: p [128][17]

    const int tid  = threadIdx.x;
    const int lane = tid & 63;
    const int w    = tid >> 6;
    const int q    = lane >> 4;
    const int col  = lane & 15;

    const int bid = blockIdx.x;
    const int t   = bid >> 4;            // tree (blocks grouped by tree for L2 reuse of w_bt)
    const int m0  = (bid & 15) << 7;     // batch-row tile * 128

    // ---- staging descriptors: 24 issues/chunk (16 A + 8 B), 6 per wave ----
    int lds_off[6];
    const unsigned short* gsrc[6];
    #pragma unroll
    for (int i = 0; i < 6; ++i) {
        int issue = w * 6 + i;
        if (issue < 16) {                          // A: x rows
            int slot = issue * 64 + lane;          // 0..1023
            int m  = slot >> 3, kg = slot & 7;
            int sk = kg ^ (m & 7);
            lds_off[i] = slot * 16;
            gsrc[i] = x_bf + (m0 + m) * D_FEAT + sk * 8;
        } else {                                   // B: w_bt[t] rows (n-major)
            int slot = (issue - 16) * 64 + lane;   // 0..511
            int n  = slot >> 3, kg = slot & 7;
            int sk = kg ^ (n & 7);
            lds_off[i] = 16384 + slot * 16;
            gsrc[i] = w_bt + (t * 64 + n) * D_FEAT + sk * 8;
        }
    }

    const int m_a[2] = { w * 32 + col, w * 32 + 16 + col };
    const int ma7[2] = { m_a[0] & 7, m_a[1] & 7 };
    const int n_b[4] = { col, 16 + col, 32 + col, 48 + col };

    f32x4 acc[2][4];
    #pragma unroll
    for (int mi = 0; mi < 2; ++mi)
        #pragma unroll
        for (int ni = 0; ni < 4; ++ni)
            acc[mi][ni] = (f32x4){0.f, 0.f, 0.f, 0.f};

    // ---- K loop: 8 chunks of 64 ----
    for (int c = 0; c < 8; ++c) {
        __syncthreads();                               // previous compute done
        #pragma unroll
        for (int i = 0; i < 6; ++i)
            gload_lds16(gsrc[i] + c * 64, smem + lds_off[i]);
        __syncthreads();                               // staging drained (vmcnt(0) at barrier)
        #pragma unroll
        for (int s = 0; s < 2; ++s) {
            bf16x8 av[2], bv[4];
            #pragma unroll
            for (int mi = 0; mi < 2; ++mi) {
                int kgp = (s * 4 + q) ^ ma7[mi];
                av[mi] = *(const bf16x8*)(Alds + m_a[mi] * 64 + kgp * 8);
            }
            #pragma unroll
            for (int ni = 0; ni < 4; ++ni) {
                int kgp = (s * 4 + q) ^ (n_b[ni] & 7);
                bv[ni] = *(const bf16x8*)(Blds + n_b[ni] * 64 + kgp * 8);
            }
            #pragma unroll
            for (int mi = 0; mi < 2; ++mi)
                #pragma unroll
                for (int ni = 0; ni < 4; ++ni)
                    acc[mi][ni] = __builtin_amdgcn_mfma_f32_16x16x32_bf16(
                        av[mi], bv[ni], acc[mi][ni], 0, 0, 0);
        }
    }

    // ---- epilogue: h = relu(acc + b_t) -> LDS (bf16, A-layout, same swizzle) ----
    __syncthreads();                                   // all LDS reads of last chunk done
    float btv[4];
    #pragma unroll
    for (int ni = 0; ni < 4; ++ni) btv[ni] = b_t[t * 64 + n_b[ni]];
    #pragma unroll
    for (int mi = 0; mi < 2; ++mi)
        #pragma unroll
        for (int ni = 0; ni < 4; ++ni)
            #pragma unroll
            for (int r = 0; r < 4; ++r) {
                int m = w * 32 + mi * 16 + q * 4 + r;  // C/D layout: row = quad*4 + reg
                int n = n_b[ni];                       // col = lane&15 (+16*ni)
                float h = fmaxf(acc[mi][ni][r] + btv[ni], 0.f);
                int kgp = (n >> 3) ^ (m & 7);
                Alds[m * 64 + kgp * 8 + (n & 7)] = f32_to_bf16(h);
            }
    // stage w_dt[t] (16x64 bf16 = 2KB) into Blds: 2 issues on waves 0,1
    if (w < 2) {
        int slot = w * 64 + lane;                      // 0..127
        int l  = slot >> 3, kg = slot & 7;
        int sk = kg ^ (l & 7);
        gload_lds16(w_dt + t * 1024 + l * 64 + sk * 8, smem + 16384 + slot * 16);
    }
    __syncthreads();

    // ---- GEMM2: p_logit[128,16] = h @ w_d^T, K=64 (2 mfma k-steps) ----
    f32x4 acc2[2] = { (f32x4){0.f,0.f,0.f,0.f}, (f32x4){0.f,0.f,0.f,0.f} };
    #pragma unroll
    for (int s = 0; s < 2; ++s) {
        bf16x8 av[2], bv;
        #pragma unroll
        for (int mi = 0; mi < 2; ++mi) {
            int kgp = (s * 4 + q) ^ ma7[mi];
            av[mi] = *(const bf16x8*)(Alds + m_a[mi] * 64 + kgp * 8);
        }
        {
            int kgp = (s * 4 + q) ^ (col & 7);
            bv = *(const bf16x8*)(Blds + col * 64 + kgp * 8);
        }
        #pragma unroll
        for (int mi = 0; mi < 2; ++mi)
            acc2[mi] = __builtin_amdgcn_mfma_f32_16x16x32_bf16(av[mi], bv, acc2[mi], 0, 0, 0);
    }
    // p = sigmoid(logit + b_d); col 15 is pad (never read)
    float bdv = (col < 15) ? b_d[t * 15 + col] : 0.f;
    #pragma unroll
    for (int mi = 0; mi < 2; ++mi)
        #pragma unroll
        for (int r = 0; r < 4; ++r) {
            int m = w * 32 + mi * 16 + q * 4 + r;
            float lg = acc2[mi][r] + bdv;
            Plds[m * 17 + col] = 1.f / (1.f + __expf(-lg));
        }
    __syncthreads();

    // ---- soft routing mu + leaf score f = tanh(mu . w_l + b_l) ----
    if (tid < 128) {
        int m = tid;
        float pv[15];
        #pragma unroll
        for (int i = 0; i < 15; ++i) pv[i] = Plds[m * 17 + i];
        float facc = 0.f;
        #pragma unroll
        for (int leaf = 0; leaf < 16; ++leaf) {
            float mu = 1.f;
            int node = 0;
            #pragma unroll
            for (int d = 0; d < 4; ++d) {
                int bit = (leaf >> (3 - d)) & 1;
                float p = pv[node];                 // node is a constant after unroll
                mu *= bit ? (1.f - p) : p;
                node = 2 * node + 1 + bit;
            }
            facc += mu * w_l[t * 16 + leaf];
        }
        f_ws[t * BATCH + m0 + m] = tanhf(facc + b_l[t]);
    }
}

// ---------------- boosting prefix-sum ----------------
// out[b][0] = f0; out[b][1+k] = f0 + LR * sum_{i<=k} f[i][b]
__global__ void scan_k(const float* __restrict__ f_ws, const float* __restrict__ f0p,
                       float* __restrict__ out) {
    int b = blockIdx.x, tid = threadIdx.x;
    int lane = tid & 63, wid = tid >> 6;
    float f0 = f0p[0];
    float x = (tid < T_TREES) ? f_ws[tid * BATCH + b] : 0.f;
    #pragma unroll
    for (int off = 1; off < 64; off <<= 1) {
        float y = __shfl_up(x, off, 64);
        if (lane >= off) x += y;
    }
    __shared__ float wsum[4];
    if (lane == 63) wsum[wid] = x;
    __syncthreads();
    float base = 0.f;
    for (int i = 0; i < wid; ++i) base += wsum[i];
    float incl = x + base;
    if (tid == 0) out[b * (T_TREES + 1)] = f0;
    if (tid < T_TREES) out[b * (T_TREES + 1) + 1 + tid] = f0 + LR * incl;
}

extern "C" void kernel_launch(void* const* d_in, const int* in_sizes, int n_in,
                              void* d_out, int out_size, void* d_ws, size_t ws_size,
                              hipStream_t stream) {
    const float* x   = (const float*)d_in[0];
    // d_in[1] = y_true (unused by forward output)
    const float* w_t = (const float*)d_in[2];
    const float* b_t = (const float*)d_in[3];
    const float* w_d = (const float*)d_in[4];
    const float* b_d = (const float*)d_in[5];
    const float* w_l = (const float*)d_in[6];
    const float* b_l = (const float*)d_in[7];
    const float* f_0 = (const float*)d_in[8];
    float* out = (float*)d_out;

    char* ws = (char*)d_ws;
    unsigned short* x_bf = (unsigned short*)(ws);               // 2,097,152 B
    unsigned short* w_bt = (unsigned short*)(ws + 2097152);     // 13,107,200 B
    unsigned short* w_dt = (unsigned short*)(ws + 15204352);    // 409,600 B
    float*          f_ws = (float*)(ws + 15613952);             // 1,638,400 B (ends ~16.5 MB)

    prep_x  <<<1024, 256, 0, stream>>>(x, x_bf);
    prep_wt <<<6400, 256, 0, stream>>>(w_t, w_bt);
    prep_wd <<< 800, 256, 0, stream>>>(w_d, w_dt);
    gbdt_main<<<T_TREES * (BATCH / 128), 256, 0, stream>>>(
        x_bf, w_bt, w_dt, b_t, b_d, w_l, b_l, f_ws);
    scan_k<<<BATCH, 256, 0, stream>>>(f_ws, f_0, out);
}

// Round 2
// 140.416 us; speedup vs baseline: 1.1855x; 1.1855x over previous
//
#include <hip/hip_runtime.h>

// Problem constants (from reference)
#define T_TREES 200
#define BATCH   2048
#define D_FEAT  512
#define N_NODE  64
#define LR      0.01f

typedef __attribute__((__ext_vector_type__(8))) __bf16 bf16x8;
typedef __attribute__((__ext_vector_type__(4))) float  f32x4;

__device__ __forceinline__ unsigned short f32_to_bf16(float f) {
    unsigned u = __float_as_uint(f);
    u += 0x7FFFu + ((u >> 16) & 1u);   // RNE
    return (unsigned short)(u >> 16);
}

__device__ __forceinline__ void gload_lds16(const void* g, void* l) {
    __builtin_amdgcn_global_load_lds(
        (__attribute__((address_space(1))) void*)(void*)g,
        (__attribute__((address_space(3))) void*)l,
        16, 0, 0);
}

// ---------------- prep kernels ----------------

// x [2048][512] f32 -> bf16 (same layout)
__global__ void prep_x(const float* __restrict__ x, unsigned short* __restrict__ xb) {
    int i = blockIdx.x * 256 + threadIdx.x;           // 262144 float4 groups
    float4 v = ((const float4*)x)[i];
    ushort4 o;
    o.x = f32_to_bf16(v.x); o.y = f32_to_bf16(v.y);
    o.z = f32_to_bf16(v.z); o.w = f32_to_bf16(v.w);
    ((ushort4*)xb)[i] = o;
}

// w_t [t][d][n] f32 -> w_bt [t][n][d] bf16, transposed through LDS (coalesced both sides).
// grid 1600: block = (t, slab); slab = 64 d-rows.
__global__ __launch_bounds__(256) void prep_wt(const float* __restrict__ w_t,
                                               unsigned short* __restrict__ w_bt) {
    __shared__ float tile[64 * 65];
    int t = blockIdx.x >> 3, slab = blockIdx.x & 7;
    const float* src = w_t + t * (D_FEAT * N_NODE) + slab * 4096;   // [64 d][64 n]
    #pragma unroll
    for (int p = 0; p < 16; ++p) {
        int idx = p * 256 + threadIdx.x;              // coalesced read
        tile[(idx >> 6) * 65 + (idx & 63)] = src[idx];
    }
    __syncthreads();
    unsigned short* dst = w_bt + t * (N_NODE * D_FEAT) + slab * 64; // row n stride 512
    #pragma unroll
    for (int p = 0; p < 8; ++p) {
        int idx = p * 256 + threadIdx.x;
        int n = idx >> 5, d = (idx & 31) * 2;
        ushort2 o;
        o.x = f32_to_bf16(tile[d * 65 + n]);
        o.y = f32_to_bf16(tile[(d + 1) * 65 + n]);
        *(ushort2*)(dst + n * D_FEAT + d) = o;        // coalesced 4B stores
    }
}

// w_d [t][n][15] f32 -> w_dt [t][16][64] bf16 (transposed, col 15 zero-padded)
__global__ void prep_wd(const float* __restrict__ w_d, unsigned short* __restrict__ w_dt) {
    int i = blockIdx.x * 256 + threadIdx.x;           // 204800 = 200*16*64
    int n = i & 63;
    int l = (i >> 6) & 15;
    int t = i >> 10;
    float v = (l < 15) ? w_d[(t * 64 + n) * 15 + l] : 0.f;
    w_dt[i] = f32_to_bf16(v);
}

// ---------------- main fused kernel ----------------
// One block = TWO trees x 128 batch rows. 1600 blocks, 256 threads (4 waves).
// GEMM1: [128,512] @ [512,128] (two trees' weights, contiguous rows in w_bt).
// 32 mfma per wave per K-chunk (2x the round-1 kernel) -> better mfma:barrier ratio.
// LDS XOR swizzle (kg ^= row&7): dense for global_load_lds, conflict-free ds_read_b128.
__global__ __launch_bounds__(256) void gbdt_main(
    const unsigned short* __restrict__ x_bf,   // [2048][512] bf16
    const unsigned short* __restrict__ w_bt,   // [200][64][512] bf16
    const unsigned short* __restrict__ w_dt,   // [200][16][64] bf16
    const float* __restrict__ b_t,             // [200][64]
    const float* __restrict__ b_d,             // [200][15]
    const float* __restrict__ w_l,             // [200][16]
    const float* __restrict__ b_l,             // [200]
    float* __restrict__ f_ws)                  // [200][2048]
{
    // Layout: [0,16384) A tile (x, 128x64 bf16) | [16384,20480) Wd (32x64 bf16)
    //         [20480,53248) B tile (w pair, 128 rows x 64 k bf16) / later h (128x128 bf16)
    // P (128 x 2 x 17 f32 = 17408 B) overlays [0,17408) after GEMM2.
    __shared__ alignas(16) char smem[53248];
    unsigned short* Alds = (unsigned short*)smem;
    unsigned short* Wlds = (unsigned short*)(smem + 16384);
    unsigned short* Blds = (unsigned short*)(smem + 20480);
    float*          Plds = (float*)smem;

    const int tid  = threadIdx.x;
    const int lane = tid & 63;
    const int w    = tid >> 6;
    const int q    = lane >> 4;
    const int col  = lane & 15;

    const int bid  = blockIdx.x;
    const int pair = bid >> 4;           // 0..99
    const int t0   = pair * 2;
    const int m0   = (bid & 15) << 7;    // batch-row tile * 128

    // ---- staging descriptors: 32 issues/chunk (16 A + 16 B), 8 per wave ----
    int lds_off[8];
    const unsigned short* gsrc[8];
    #pragma unroll
    for (int i = 0; i < 8; ++i) {
        int issue = w * 8 + i;
        if (issue < 16) {                          // A: x rows
            int slot = issue * 64 + lane;          // 0..1023
            int m  = slot >> 3, kg = slot & 7;
            int sk = kg ^ (m & 7);
            lds_off[i] = slot * 16;
            gsrc[i] = x_bf + (m0 + m) * D_FEAT + sk * 8;
        } else {                                   // B: w_bt rows t0*64 .. t0*64+127
            int slot = (issue - 16) * 64 + lane;   // 0..1023
            int n  = slot >> 3, kg = slot & 7;     // n' = 0..127
            int sk = kg ^ (n & 7);
            lds_off[i] = 20480 + slot * 16;
            gsrc[i] = w_bt + (t0 * 64 + n) * D_FEAT + sk * 8;
        }
    }
    // Wd staging (once, during chunk 0): 4 issues, 1 per wave
    const unsigned short* wd_src;
    int wd_off;
    {
        int slot = w * 64 + lane;                  // 0..255 -> 32 rows x 8 kg
        int l  = slot >> 3, kg = slot & 7;
        int sk = kg ^ (l & 7);
        wd_off = 16384 + slot * 16;
        wd_src = w_dt + t0 * 1024 + l * 64 + sk * 8;
    }

    const int m_a[2] = { w * 32 + col, w * 32 + 16 + col };
    const int c7     = col & 7;

    f32x4 acc[2][8];
    #pragma unroll
    for (int mi = 0; mi < 2; ++mi)
        #pragma unroll
        for (int ni = 0; ni < 8; ++ni)
            acc[mi][ni] = (f32x4){0.f, 0.f, 0.f, 0.f};

    // ---- K loop: 8 chunks of 64 ----
    for (int c = 0; c < 8; ++c) {
        __syncthreads();                               // previous compute done
        #pragma unroll
        for (int i = 0; i < 8; ++i)
            gload_lds16(gsrc[i] + c * 64, smem + lds_off[i]);
        if (c == 0)
            gload_lds16(wd_src, smem + wd_off);
        __syncthreads();                               // staging drained
        #pragma unroll
        for (int s = 0; s < 2; ++s) {
            bf16x8 av[2], bv[8];
            #pragma unroll
            for (int mi = 0; mi < 2; ++mi) {
                int kgp = (s * 4 + q) ^ c7;            // m_a&7 == col&7
                av[mi] = *(const bf16x8*)(Alds + m_a[mi] * 64 + kgp * 8);
            }
            #pragma unroll
            for (int ni = 0; ni < 8; ++ni) {
                int np  = ni * 16 + col;               // n' 0..127
                int kgp = (s * 4 + q) ^ c7;            // np&7 == col&7
                bv[ni] = *(const bf16x8*)(Blds + np * 64 + kgp * 8);
            }
            #pragma unroll
            for (int mi = 0; mi < 2; ++mi)
                #pragma unroll
                for (int ni = 0; ni < 8; ++ni)
                    acc[mi][ni] = __builtin_amdgcn_mfma_f32_16x16x32_bf16(
                        av[mi], bv[ni], acc[mi][ni], 0, 0, 0);
        }
    }

    // ---- epilogue: h = relu(acc + b_t) -> Blds (bf16, A-layout for GEMM2) ----
    __syncthreads();                                   // all GEMM1 LDS reads done
    float btv[8];
    #pragma unroll
    for (int ni = 0; ni < 8; ++ni) btv[ni] = b_t[t0 * 64 + ni * 16 + col];
    unsigned short* Hlds = Blds;                       // h: [128 m][128 c] bf16, swizzled
    #pragma unroll
    for (int mi = 0; mi < 2; ++mi)
        #pragma unroll
        for (int ni = 0; ni < 8; ++ni)
            #pragma unroll
            for (int r = 0; r < 4; ++r) {
                int m  = w * 32 + mi * 16 + q * 4 + r; // C/D layout: row = quad*4 + reg
                int cc = ni * 16 + col;                // col = lane&15 (+16*ni)
                float h = fmaxf(acc[mi][ni][r] + btv[ni], 0.f);
                int g  = cc >> 3;
                int gp = (g & 8) | ((g ^ m) & 7);      // XOR-swizzle low 3 bits
                Hlds[m * 128 + gp * 8 + (cc & 7)] = f32_to_bf16(h);
            }
    __syncthreads();                                   // h visible; Wd resident since c=0

    // ---- GEMM2: per tree j, p_logit[128,16] = h_j @ w_d_j^T, K=64 ----
    f32x4 acc2[2][2];
    #pragma unroll
    for (int j = 0; j < 2; ++j)
        #pragma unroll
        for (int mi = 0; mi < 2; ++mi)
            acc2[j][mi] = (f32x4){0.f, 0.f, 0.f, 0.f};
    #pragma unroll
    for (int s = 0; s < 2; ++s) {
        int kg2 = s * 4 + q;
        bf16x8 bvw[2], avh[2][2];
        #pragma unroll
        for (int j = 0; j < 2; ++j) {
            int lp  = j * 16 + col;                    // Wd row
            int kgp = kg2 ^ c7;
            bvw[j] = *(const bf16x8*)(Wlds + lp * 64 + kgp * 8);
            #pragma unroll
            for (int mi = 0; mi < 2; ++mi) {
                int m  = m_a[mi];
                int gp = j * 8 + ((kg2 ^ (m & 7)) & 7);
                avh[j][mi] = *(const bf16x8*)(Hlds + m * 128 + gp * 8);
            }
        }
        #pragma unroll
        for (int j = 0; j < 2; ++j)
            #pragma unroll
            for (int mi = 0; mi < 2; ++mi)
                acc2[j][mi] = __builtin_amdgcn_mfma_f32_16x16x32_bf16(
                    avh[j][mi], bvw[j], acc2[j][mi], 0, 0, 0);
    }
    __syncthreads();                                   // GEMM2 LDS reads done (P overlays A/Wd)

    // p = sigmoid(logit + b_d) -> Plds [128][2][17] f32
    float bdv[2];
    #pragma unroll
    for (int j = 0; j < 2; ++j)
        bdv[j] = (col < 15) ? b_d[(t0 + j) * 15 + col] : 0.f;
    #pragma unroll
    for (int j = 0; j < 2; ++j)
        #pragma unroll
        for (int mi = 0; mi < 2; ++mi)
            #pragma unroll
            for (int r = 0; r < 4; ++r) {
                int m = w * 32 + mi * 16 + q * 4 + r;
                float lg = acc2[j][mi][r] + bdv[j];
                Plds[m * 34 + j * 17 + col] = 1.f / (1.f + __expf(-lg));
            }
    __syncthreads();

    // ---- soft routing mu + leaf score, all 256 threads: (m, tree j) ----
    {
        int m = tid & 127;
        int j = tid >> 7;
        int t = t0 + j;
        float pv[15];
        #pragma unroll
        for (int i = 0; i < 15; ++i) pv[i] = Plds[m * 34 + j * 17 + i];
        float facc = 0.f;
        #pragma unroll
        for (int leaf = 0; leaf < 16; ++leaf) {
            float mu = 1.f;
            int node = 0;
            #pragma unroll
            for (int d = 0; d < 4; ++d) {
                int bit = (leaf >> (3 - d)) & 1;
                float p = pv[node];
                mu *= bit ? (1.f - p) : p;
                node = 2 * node + 1 + bit;
            }
            facc += mu * w_l[t * 16 + leaf];
        }
        f_ws[t * BATCH + m0 + m] = tanhf(facc + b_l[t]);  // coalesced per 128-run
    }
}

// ---------------- boosting prefix-sum ----------------
__global__ void scan_k(const float* __restrict__ f_ws, const float* __restrict__ f0p,
                       float* __restrict__ out) {
    int b = blockIdx.x, tid = threadIdx.x;
    int lane = tid & 63, wid = tid >> 6;
    float f0 = f0p[0];
    float x = (tid < T_TREES) ? f_ws[tid * BATCH + b] : 0.f;
    #pragma unroll
    for (int off = 1; off < 64; off <<= 1) {
        float y = __shfl_up(x, off, 64);
        if (lane >= off) x += y;
    }
    __shared__ float wsum[4];
    if (lane == 63) wsum[wid] = x;
    __syncthreads();
    float base = 0.f;
    for (int i = 0; i < wid; ++i) base += wsum[i];
    float incl = x + base;
    if (tid == 0) out[b * (T_TREES + 1)] = f0;
    if (tid < T_TREES) out[b * (T_TREES + 1) + 1 + tid] = f0 + LR * incl;
}

extern "C" void kernel_launch(void* const* d_in, const int* in_sizes, int n_in,
                              void* d_out, int out_size, void* d_ws, size_t ws_size,
                              hipStream_t stream) {
    const float* x   = (const float*)d_in[0];
    const float* w_t = (const float*)d_in[2];
    const float* b_t = (const float*)d_in[3];
    const float* w_d = (const float*)d_in[4];
    const float* b_d = (const float*)d_in[5];
    const float* w_l = (const float*)d_in[6];
    const float* b_l = (const float*)d_in[7];
    const float* f_0 = (const float*)d_in[8];
    float* out = (float*)d_out;

    char* ws = (char*)d_ws;
    unsigned short* x_bf = (unsigned short*)(ws);               // 2,097,152 B
    unsigned short* w_bt = (unsigned short*)(ws + 2097152);     // 13,107,200 B
    unsigned short* w_dt = (unsigned short*)(ws + 15204352);    // 409,600 B
    float*          f_ws = (float*)(ws + 15613952);             // 1,638,400 B

    prep_x  <<<1024, 256, 0, stream>>>(x, x_bf);
    prep_wt <<<1600, 256, 0, stream>>>(w_t, w_bt);
    prep_wd <<< 800, 256, 0, stream>>>(w_d, w_dt);
    gbdt_main<<<100 * (BATCH / 128), 256, 0, stream>>>(
        x_bf, w_bt, w_dt, b_t, b_d, w_l, b_l, f_ws);
    scan_k<<<BATCH, 256, 0, stream>>>(f_ws, f_0, out);
}